// Round 8
// baseline (157.124 us; speedup 1.0000x reference)
//
#include <hip/hip_runtime.h>
#include <hip/hip_bf16.h>

typedef __bf16 bf16;
typedef bf16 bf16x8 __attribute__((ext_vector_type(8)));
typedef bf16 bf16x4 __attribute__((ext_vector_type(4)));
typedef float f32x4 __attribute__((ext_vector_type(4)));
typedef short s16x4 __attribute__((ext_vector_type(4)));
typedef unsigned u32x2 __attribute__((ext_vector_type(2)));

#define MFMA16(a,b,c)   __builtin_amdgcn_mfma_f32_16x16x32_bf16(a,b,c,0,0,0)
#define MFMA1616(a,b,c) __builtin_amdgcn_mfma_f32_16x16x16bf16_1k(a,b,c,0,0,0)

// async global->LDS, 16B per lane; LDS dest = wave-uniform base + lane*16
__device__ inline void gload_lds16(const bf16* g, bf16* l) {
  __builtin_amdgcn_global_load_lds(
      (const __attribute__((address_space(1))) unsigned int*)g,
      (__attribute__((address_space(3))) unsigned int*)l,
      16, 0, 0);
}

// swizzled fragment read: glob[r][cb*8..+8] lives at lds r*64 + (cb^(r&7))*8
__device__ inline bf16x8 ldsfrag(const bf16* base, int r, int cb) {
  return *(const bf16x8*)(base + r*64 + ((cb ^ (r & 7)) << 3));
}

// pack two fp32 into one u32 of 2 bf16 (RNE via scalar casts; compiler packs)
__device__ inline unsigned pack2(float lo, float hi) {
  unsigned short a = __builtin_bit_cast(unsigned short, (bf16)lo);
  unsigned short b = __builtin_bit_cast(unsigned short, (bf16)hi);
  return (unsigned)a | ((unsigned)b << 16);
}
__device__ inline s16x4 mk4(unsigned lo, unsigned hi) {
  u32x2 t; t[0] = lo; t[1] = hi;
  return __builtin_bit_cast(s16x4, t);
}

// ---------------------------------------------------------------------------
// Bulk fp32 -> bf16 conversion. y selects the array.
// ---------------------------------------------------------------------------
__global__ __launch_bounds__(256) void cvt_kernel(
    const float* __restrict__ q, const float* __restrict__ k_, const float* __restrict__ v,
    const float* __restrict__ Wq, const float* __restrict__ Wk, const float* __restrict__ Wv,
    const float* __restrict__ fcw,
    bf16* __restrict__ qb, bf16* __restrict__ kb, bf16* __restrict__ vb,
    bf16* __restrict__ Wqb, bf16* __restrict__ Wkb, bf16* __restrict__ Wvb,
    bf16* __restrict__ fcwb)
{
  const int y = blockIdx.y;
  const float* src; bf16* dst; int n;
  if      (y==0) { src=q;   dst=qb;   n=4194304; }
  else if (y==1) { src=k_;  dst=kb;   n=4194304; }
  else if (y==2) { src=v;   dst=vb;   n=4194304; }
  else if (y==3) { src=Wq;  dst=Wqb;  n=262144;  }
  else if (y==4) { src=Wk;  dst=Wkb;  n=262144;  }
  else if (y==5) { src=Wv;  dst=Wvb;  n=262144;  }
  else           { src=fcw; dst=fcwb; n=262144;  }
  const int i = (blockIdx.x*256 + threadIdx.x)*4;
  if (i >= n) return;
  f32x4 x = *(const f32x4*)(src + i);
  bf16x4 o;
  o[0]=(bf16)x[0]; o[1]=(bf16)x[1]; o[2]=(bf16)x[2]; o[3]=(bf16)x[3];
  *(bf16x4*)(dst + i) = o;
}

// ---------------------------------------------------------------------------
// QKV projection v7 (unchanged): LDS double-buffered GEMM.
// ---------------------------------------------------------------------------
__global__ __launch_bounds__(256) void proj_kernel(
    const bf16* __restrict__ qb, const bf16* __restrict__ kb, const bf16* __restrict__ vb,
    const bf16* __restrict__ Wqb, const bf16* __restrict__ Wkb, const bf16* __restrict__ Wvb,
    bf16* __restrict__ qh, bf16* __restrict__ kh, bf16* __restrict__ vhT)
{
  const int p = blockIdx.z;
  const bf16* A = (p==0)?qb:(p==1)?kb:vb;
  const bf16* W = (p==0)?Wqb:(p==1)?Wkb:Wvb;
  const int m0 = blockIdx.x*128, n0 = blockIdx.y*64;
  const int l  = threadIdx.x & 63, w = threadIdx.x >> 6;
  const int lr = l & 15, lh = l >> 4;

  __shared__ bf16 sA[2][8192];
  __shared__ bf16 sW[2][4096];

  auto stageA = [&](bf16* d, int kk) {
#pragma unroll
    for (int c = 0; c < 4; ++c) {
      const int i   = (w*4 + c)*64 + l;
      const int r   = i >> 3;
      const int cbs = (i & 7) ^ (r & 7);
      gload_lds16(A + (size_t)(m0 + r)*512 + kk + cbs*8, d + (w*4+c)*512);
    }
  };
  auto stageW = [&](bf16* d, int kk) {
#pragma unroll
    for (int c = 0; c < 2; ++c) {
      const int i   = (w*2 + c)*64 + l;
      const int r   = i >> 3;
      const int cbs = (i & 7) ^ (r & 7);
      gload_lds16(W + (size_t)(n0 + r)*512 + kk + cbs*8, d + (w*2+c)*512);
    }
  };

  stageA(sA[0], 0); stageW(sW[0], 0);
  __syncthreads();

  f32x4 zero = {0.f,0.f,0.f,0.f};
  f32x4 acc[2][4] = {{zero,zero,zero,zero},{zero,zero,zero,zero}};

  int cur = 0;
#pragma unroll 1
  for (int kk = 0; kk < 512; kk += 64) {
    if (kk + 64 < 512) { stageA(sA[cur^1], kk+64); stageW(sW[cur^1], kk+64); }
    const bf16* a_ = sA[cur];
    const bf16* w_ = sW[cur];
#pragma unroll
    for (int s = 0; s < 2; ++s) {
      bf16x8 a0 = ldsfrag(a_, w*32 + lr,      s*4 + lh);
      bf16x8 a1 = ldsfrag(a_, w*32 + 16 + lr, s*4 + lh);
#pragma unroll
      for (int t = 0; t < 4; ++t) {
        bf16x8 wf = ldsfrag(w_, t*16 + lr, s*4 + lh);
        acc[0][t] = MFMA16(a0, wf, acc[0][t]);
        acc[1][t] = MFMA16(a1, wf, acc[1][t]);
      }
    }
    __syncthreads();
    cur ^= 1;
  }

  const float qscale = 0.18033688011112042f;  // 0.125 * log2(e)
#pragma unroll
  for (int g = 0; g < 2; ++g)
#pragma unroll
    for (int t = 0; t < 4; ++t) {
      const int ncol = n0 + t*16 + lr;
      const int h = ncol >> 6, d = ncol & 63;
#pragma unroll
      for (int j = 0; j < 4; ++j) {
        const int m   = m0 + w*32 + g*16 + lh*4 + j;
        const int b   = m >> 11, tok = m & 2047;
        float val = acc[g][t][j];
        if (p == 0) val *= qscale;
        const bf16 bv = (bf16)val;
        if (p == 0)      qh [((size_t)((h<<2)|b)*2048 + tok)*64 + d]   = bv;
        else if (p == 1) kh [((size_t)((h<<2)|b)*2048 + tok)*64 + d]   = bv;
        else             vhT[((size_t)((h<<2)|b)*64   + d)*2048 + tok] = bv;
      }
    }
}

// ---------------------------------------------------------------------------
// Attention v8: swapped QK^T (mfma(K,Q) -> lane holds S^T: q=lr, k=t*16+lh*4+j)
// feeds PV directly as 16x16x16 A-fragments — NO sP roundtrip, no drains.
// LDS double-buffered K/V via global_load_lds + XOR swizzle (unchanged).
// Unnormalized exp2-clamped softmax; per-lane scalar deferred sum.
// ---------------------------------------------------------------------------
__global__ __launch_bounds__(256, 3) void attn_kernel(
    const bf16* __restrict__ qh, const bf16* __restrict__ kh, const bf16* __restrict__ vhT,
    const int* __restrict__ mask, float* __restrict__ attn_out)
{
  const int n  = blockIdx.y;
  const int w  = threadIdx.x >> 6;
  const int l  = threadIdx.x & 63;
  const int lr = l & 15, lh = l >> 4;
  const int q0 = blockIdx.x*128 + w*32;
  const bf16* qn = qh  + (size_t)n*2048*64;
  const bf16* kn = kh  + (size_t)n*2048*64;
  const bf16* vn = vhT + (size_t)n*64*2048;
  const int h = n >> 2, b = n & 3;

  __shared__ float smask[2048];
  __shared__ bf16  sK[2][4096];
  __shared__ bf16  sV[2][4096];

  auto stage = [&](bf16* dK, bf16* dV, int kt_) {
#pragma unroll
    for (int c = 0; c < 2; ++c) {
      const int i   = (w*2 + c)*64 + l;
      const int r   = i >> 3;
      const int cbs = (i & 7) ^ (r & 7);
      gload_lds16(kn + (size_t)(kt_ + r)*64   + cbs*8, dK + (w*2+c)*512);
      gload_lds16(vn + (size_t)r*2048 + kt_   + cbs*8, dV + (w*2+c)*512);
    }
  };

  {
    const int* mn = mask + n*2048;
    const int i0 = (int)threadIdx.x * 8;
    int4 m0v = *(const int4*)(mn + i0);
    int4 m1v = *(const int4*)(mn + i0 + 4);
    f32x4 f0, f1;
    f0[0]=m0v.x?1.f:0.f; f0[1]=m0v.y?1.f:0.f; f0[2]=m0v.z?1.f:0.f; f0[3]=m0v.w?1.f:0.f;
    f1[0]=m1v.x?1.f:0.f; f1[1]=m1v.y?1.f:0.f; f1[2]=m1v.z?1.f:0.f; f1[3]=m1v.w?1.f:0.f;
    *(f32x4*)(smask + i0)     = f0;
    *(f32x4*)(smask + i0 + 4) = f1;
  }
  stage(sK[0], sV[0], 0);
  __syncthreads();

  bf16x8 aq[2][2];
#pragma unroll
  for (int g = 0; g < 2; ++g) {
    aq[g][0] = *(const bf16x8*)(qn + (size_t)(q0+g*16+lr)*64 + lh*8);
    aq[g][1] = *(const bf16x8*)(qn + (size_t)(q0+g*16+lr)*64 + 32 + lh*8);
  }

  f32x4 zero = {0.f,0.f,0.f,0.f};
  f32x4 acc[2][4] = {{zero,zero,zero,zero},{zero,zero,zero,zero}};
  float ssum[2] = {0.f, 0.f};

  int cur = 0;
#pragma unroll 1
  for (int kt = 0; kt < 2048; kt += 64) {
    const int ktn = kt + 64;
    if (ktn < 2048) stage(sK[cur^1], sV[cur^1], ktn);

    const bf16* sKc = sK[cur];
    const bf16* sVc = sV[cur];

    // ---- S^T = K Q^T : lane (lr,lh) gets S[k=t*16+lh*4+j][q=lr]
    f32x4 sc[2][4] = {{zero,zero,zero,zero},{zero,zero,zero,zero}};
#pragma unroll
    for (int t = 0; t < 4; ++t) {
      bf16x8 bk0 = ldsfrag(sKc, t*16 + lr, lh);
      bf16x8 bk1 = ldsfrag(sKc, t*16 + lr, lh + 4);
      sc[0][t] = MFMA16(bk0, aq[0][0], sc[0][t]);
      sc[0][t] = MFMA16(bk1, aq[0][1], sc[0][t]);
      sc[1][t] = MFMA16(bk0, aq[1][0], sc[1][t]);
      sc[1][t] = MFMA16(bk1, aq[1][1], sc[1][t]);
    }
    // ---- softmax (unnormalized, clamped) + pack into 16x16x16 A-frags
    s16x4 pa[2][4];
#pragma unroll
    for (int t = 0; t < 4; ++t) {
      const f32x4 m4 = *(const f32x4*)(smask + kt + t*16 + lh*4);
#pragma unroll
      for (int g = 0; g < 2; ++g) {
        float e0 = exp2f(fminf(sc[g][t][0], 100.f)) * m4[0];
        float e1 = exp2f(fminf(sc[g][t][1], 100.f)) * m4[1];
        float e2 = exp2f(fminf(sc[g][t][2], 100.f)) * m4[2];
        float e3 = exp2f(fminf(sc[g][t][3], 100.f)) * m4[3];
        ssum[g] += (e0 + e1) + (e2 + e3);
        pa[g][t] = mk4(pack2(e0, e1), pack2(e2, e3));
      }
    }
    // ---- PV: 16x16x16 MFMAs, V B-frags read as b64 from swizzled sV
#pragma unroll
    for (int t = 0; t < 4; ++t) {
      const int cb = 2*t + (lh >> 1);
#pragma unroll
      for (int dt = 0; dt < 4; ++dt) {
        const int r = dt*16 + lr;
        s16x4 vb = *(const s16x4*)(sVc + r*64 + ((cb ^ (r & 7)) << 3) + (lh & 1)*4);
        acc[0][dt] = MFMA1616(pa[0][t], vb, acc[0][dt]);
        acc[1][dt] = MFMA1616(pa[1][t], vb, acc[1][dt]);
      }
    }
    __syncthreads();
    cur ^= 1;
  }

  // ---- finish: full row-sum for q=lr, redistribute to C layout, store
#pragma unroll
  for (int g = 0; g < 2; ++g) {
    ssum[g] += __shfl_xor(ssum[g], 16, 64);
    ssum[g] += __shfl_xor(ssum[g], 32, 64);
  }
#pragma unroll
  for (int g = 0; g < 2; ++g) {
    float inv[4];
#pragma unroll
    for (int j = 0; j < 4; ++j) {
      const float sq = __shfl(ssum[g], lh*4 + j, 16);   // lane lr'=lh*4+j holds q=lh*4+j
      inv[j] = (sq > 0.f) ? 1.f/sq : 0.f;
    }
#pragma unroll
    for (int dt = 0; dt < 4; ++dt)
#pragma unroll
      for (int j = 0; j < 4; ++j) {
        const int tok = q0 + g*16 + lh*4 + j;
        const int dv  = dt*16 + lr;
        attn_out[((size_t)(b*2048 + tok))*512 + h*64 + dv] = acc[g][dt][j]*inv[j];
      }
  }
}

// ---------------------------------------------------------------------------
// LayerNorm of (xa + xb), wave per row. outb (bf16 copy) optional.
// NOTE: no __restrict__ on xa/outf — ln2 runs in-place on d_out.
// ---------------------------------------------------------------------------
__global__ __launch_bounds__(256) void ln_kernel(
    const float* xa, const float* xb,
    const float* __restrict__ g, const float* __restrict__ bb,
    float* outf, bf16* outb)
{
  const int row = blockIdx.x*4 + (threadIdx.x >> 6);
  const int l   = threadIdx.x & 63;
  const float* pa = xa + (size_t)row*512;
  const float* pb = xb + (size_t)row*512;
  f32x4 u0 = *(const f32x4*)(pa + 4*l);
  f32x4 u1 = *(const f32x4*)(pa + 256 + 4*l);
  f32x4 w0 = *(const f32x4*)(pb + 4*l);
  f32x4 w1 = *(const f32x4*)(pb + 256 + 4*l);
  u0 = u0 + w0; u1 = u1 + w1;
  float s = 0.f, sq = 0.f;
#pragma unroll
  for (int e = 0; e < 4; ++e) { s += u0[e] + u1[e]; sq += u0[e]*u0[e] + u1[e]*u1[e]; }
#pragma unroll
  for (int off = 1; off < 64; off <<= 1) {
    s  += __shfl_xor(s,  off, 64);
    sq += __shfl_xor(sq, off, 64);
  }
  const float mean = s * (1.f/512.f);
  const float var  = fmaxf(sq * (1.f/512.f) - mean*mean, 0.f);
  const float r    = rsqrtf(var + 1e-5f);
  f32x4 g0v = *(const f32x4*)(g + 4*l),  g1v = *(const f32x4*)(g + 256 + 4*l);
  f32x4 b0v = *(const f32x4*)(bb + 4*l), b1v = *(const f32x4*)(bb + 256 + 4*l);
  f32x4 o0, o1;
#pragma unroll
  for (int e = 0; e < 4; ++e) {
    o0[e] = (u0[e] - mean)*r*g0v[e] + b0v[e];
    o1[e] = (u1[e] - mean)*r*g1v[e] + b1v[e];
  }
  *(f32x4*)(outf + (size_t)row*512 + 4*l)       = o0;
  *(f32x4*)(outf + (size_t)row*512 + 256 + 4*l) = o1;
  if (outb) {
    bf16x4 ob0, ob1;
#pragma unroll
    for (int e = 0; e < 4; ++e) { ob0[e]=(bf16)o0[e]; ob1[e]=(bf16)o1[e]; }
    *(bf16x4*)(outb + (size_t)row*512 + 4*l)       = ob0;
    *(bf16x4*)(outb + (size_t)row*512 + 256 + 4*l) = ob1;
  }
}

// ---------------------------------------------------------------------------
// FC v7 (unchanged): LDS double-buffered GEMM + bias, fp32 out.
// ---------------------------------------------------------------------------
__global__ __launch_bounds__(256) void fc_kernel(
    const bf16* __restrict__ A, const bf16* __restrict__ W,
    const float* __restrict__ bias, float* __restrict__ out)
{
  const int m0 = blockIdx.x*128, n0 = blockIdx.y*64;
  const int l  = threadIdx.x & 63, w = threadIdx.x >> 6;
  const int lr = l & 15, lh = l >> 4;

  __shared__ bf16 sA[2][8192];
  __shared__ bf16 sW[2][4096];

  auto stageA = [&](bf16* d, int kk) {
#pragma unroll
    for (int c = 0; c < 4; ++c) {
      const int i   = (w*4 + c)*64 + l;
      const int r   = i >> 3;
      const int cbs = (i & 7) ^ (r & 7);
      gload_lds16(A + (size_t)(m0 + r)*512 + kk + cbs*8, d + (w*4+c)*512);
    }
  };
  auto stageW = [&](bf16* d, int kk) {
#pragma unroll
    for (int c = 0; c < 2; ++c) {
      const int i   = (w*2 + c)*64 + l;
      const int r   = i >> 3;
      const int cbs = (i & 7) ^ (r & 7);
      gload_lds16(W + (size_t)(n0 + r)*512 + kk + cbs*8, d + (w*2+c)*512);
    }
  };

  stageA(sA[0], 0); stageW(sW[0], 0);
  __syncthreads();

  f32x4 zero = {0.f,0.f,0.f,0.f};
  f32x4 acc[2][4] = {{zero,zero,zero,zero},{zero,zero,zero,zero}};

  int cur = 0;
#pragma unroll 1
  for (int kk = 0; kk < 512; kk += 64) {
    if (kk + 64 < 512) { stageA(sA[cur^1], kk+64); stageW(sW[cur^1], kk+64); }
    const bf16* a_ = sA[cur];
    const bf16* w_ = sW[cur];
#pragma unroll
    for (int s = 0; s < 2; ++s) {
      bf16x8 a0 = ldsfrag(a_, w*32 + lr,      s*4 + lh);
      bf16x8 a1 = ldsfrag(a_, w*32 + 16 + lr, s*4 + lh);
#pragma unroll
      for (int t = 0; t < 4; ++t) {
        bf16x8 wf = ldsfrag(w_, t*16 + lr, s*4 + lh);
        acc[0][t] = MFMA16(a0, wf, acc[0][t]);
        acc[1][t] = MFMA16(a1, wf, acc[1][t]);
      }
    }
    __syncthreads();
    cur ^= 1;
  }

#pragma unroll
  for (int g = 0; g < 2; ++g)
#pragma unroll
    for (int t = 0; t < 4; ++t) {
      const int ncol = n0 + t*16 + lr;
      const float bs = bias[ncol];
#pragma unroll
      for (int j = 0; j < 4; ++j) {
        const int m = m0 + w*32 + g*16 + lh*4 + j;
        out[(size_t)m*512 + ncol] = acc[g][t][j] + bs;
      }
    }
}

// ---------------------------------------------------------------------------
extern "C" void kernel_launch(void* const* d_in, const int* in_sizes, int n_in,
                              void* d_out, int out_size, void* d_ws, size_t ws_size,
                              hipStream_t stream) {
  const float* q    = (const float*)d_in[0];
  const float* k    = (const float*)d_in[1];
  const float* v    = (const float*)d_in[2];
  const int*   mask = (const int*)  d_in[3];
  const float* Wq   = (const float*)d_in[4];
  const float* Wk   = (const float*)d_in[5];
  const float* Wv   = (const float*)d_in[6];
  const float* fcw  = (const float*)d_in[7];
  const float* fcb  = (const float*)d_in[8];
  const float* g0   = (const float*)d_in[9];
  const float* b0   = (const float*)d_in[10];
  const float* g1   = (const float*)d_in[11];
  const float* b1   = (const float*)d_in[12];

  char* ws = (char*)d_ws;
  // live [cvt, proj/fc]:
  bf16*  qb   = (bf16*) (ws);                                  //  8 MB [0,8)
  bf16*  kb   = (bf16*) (ws + (8ull  << 20));                  //  8 MB [8,16)
  bf16*  vb   = (bf16*) (ws + (16ull << 20));                  //  8 MB [16,24)
  bf16*  Wqb  = (bf16*) (ws + (24ull << 20));                  // [24,24.5)
  bf16*  Wkb  = (bf16*) (ws + (24ull << 20) + (512ull << 10)); // [24.5,25)
  bf16*  Wvb  = (bf16*) (ws + (25ull << 20));                  // [25,25.5)
  bf16*  fcwb = (bf16*) (ws + (25ull << 20) + (512ull << 10)); // [25.5,26)
  // live [proj, attn]:
  bf16*  qh   = (bf16*) (ws + (26ull << 20));                  //  8 MB [26,34)
  bf16*  kh   = (bf16*) (ws + (34ull << 20));                  //  8 MB [34,42)
  bf16*  vhT  = (bf16*) (ws + (42ull << 20));                  //  8 MB [42,50)
  // aliased (lifetimes disjoint):
  float* attnb= (float*)(ws);                                  // 16 MB over qb+kb (dead)
  float* x1   = (float*)(ws + (26ull << 20));                  // 16 MB over qh+kh (dead)
  bf16*  x1b  = (bf16*) (ws + (50ull << 20));                  //  8 MB [50,58) fresh
  float* out  = (float*)d_out;

  cvt_kernel <<<dim3(4096, 7), 256, 0, stream>>>(q, k, v, Wq, Wk, Wv, fcw,
                                                 qb, kb, vb, Wqb, Wkb, Wvb, fcwb);
  proj_kernel<<<dim3(64, 8, 3), 256, 0, stream>>>(qb, kb, vb, Wqb, Wkb, Wvb, qh, kh, vhT);
  attn_kernel<<<dim3(16, 32),   256, 0, stream>>>(qh, kh, vhT, mask, attnb);
  ln_kernel  <<<2048,           256, 0, stream>>>(attnb, q, g0, b0, x1, x1b);
  fc_kernel  <<<dim3(64, 8),    256, 0, stream>>>(x1b, fcwb, fcb, out);
  ln_kernel  <<<2048,           256, 0, stream>>>(out, x1, g1, b1, out, nullptr);
}